// Round 1
// baseline (194.848 us; speedup 1.0000x reference)
//
#include <hip/hip_runtime.h>

namespace {

constexpr int kB = 4, kCin = 4, kCout = 4;
constexpr int kD1 = 32, kD2 = 32, kH = 64, kW = 64;
constexpr int kHO = kH / 2, kWO = kW / 2;          // 32, 32
constexpr int kWElems = kCout * kCin * 3 * 3 * 2 * 2;  // 576

__global__ __launch_bounds__(256)
void conv4d_strang(const float* __restrict__ x,
                   const float* __restrict__ w,
                   const float* __restrict__ bias,
                   float* __restrict__ y)
{
    // Stage the tiny weight tensor into LDS (576 floats = 2.3 KB).
    __shared__ float wlds[kWElems];
    const int tid = threadIdx.y * 32 + threadIdx.x;
    for (int i = tid; i < kWElems; i += 256) wlds[i] = w[i];
    __syncthreads();

    const int wo = threadIdx.x;                     // 0..31
    const int ho = blockIdx.x * 8 + threadIdx.y;    // 0..31
    const int v  = blockIdx.y;                      // 0..31
    const int u  = blockIdx.z & 31;                 // 0..31
    const int b  = blockIdx.z >> 5;                 // 0..3

    const int h0 = 2 * ho;
    const int w0 = 2 * wo;

    float acc[kCout] = {0.f, 0.f, 0.f, 0.f};

    #pragma unroll
    for (int ku = 0; ku < 3; ++ku) {
        const int d1 = u + ku - 1;                  // pad 1 on U
        if (d1 < 0 || d1 >= kD1) continue;          // wave-uniform (u from blockIdx)
        #pragma unroll
        for (int kv = 0; kv < 3; ++kv) {
            const int d2 = v + kv - 1;              // pad 1 on V
            if (d2 < 0 || d2 >= kD2) continue;      // wave-uniform (v from blockIdx)
            #pragma unroll
            for (int ci = 0; ci < kCin; ++ci) {
                const float* xp = x +
                    (((((size_t)b * kCin + ci) * kD1 + d1) * kD2 + d2) * kH + h0) * kW + w0;
                const float2 xr0 = *reinterpret_cast<const float2*>(xp);        // h = h0,   w = w0..w0+1
                const float2 xr1 = *reinterpret_cast<const float2*>(xp + kW);   // h = h0+1
                #pragma unroll
                for (int co = 0; co < kCout; ++co) {
                    // w[co][ci][ku][kv][0..1][0..1] is 4 contiguous floats.
                    const float4 wv = *reinterpret_cast<const float4*>(
                        &wlds[(((co * kCin + ci) * 3 + ku) * 3 + kv) * 4]);
                    acc[co] += xr0.x * wv.x + xr0.y * wv.y
                             + xr1.x * wv.z + xr1.y * wv.w;
                }
            }
        }
    }

    const size_t co_stride = (size_t)kD1 * kD2 * kHO * kWO;   // 1,048,576
    const size_t obase =
        ((((size_t)b * kCout) * kD1 + u) * kD2 + v) * (size_t)(kHO * kWO)
        + (size_t)ho * kWO + wo;
    #pragma unroll
    for (int co = 0; co < kCout; ++co)
        y[obase + co * co_stride] = acc[co] + bias[co];
}

}  // namespace

extern "C" void kernel_launch(void* const* d_in, const int* in_sizes, int n_in,
                              void* d_out, int out_size, void* d_ws, size_t ws_size,
                              hipStream_t stream) {
    const float* x    = (const float*)d_in[0];
    const float* w    = (const float*)d_in[1];
    const float* bias = (const float*)d_in[2];
    float* y          = (float*)d_out;

    dim3 block(32, 8, 1);                  // wo × ho-sub
    dim3 grid(kHO / 8, kD2, kB * kD1);     // (4, 32, 128)
    hipLaunchKernelGGL(conv4d_strang, grid, block, 0, stream, x, w, bias, y);
}